// Round 1
// baseline (745.080 us; speedup 1.0000x reference)
//
#include <hip/hip_runtime.h>
#include <hip/hip_fp16.h>

// Problem: T=8192, D=2048, R=2048
//   a = sigmoid(x@W_a); b = (x@W_b)*(1-a)
//   h_t = a_t*h_{t-1} + b_t  (h_{-1} = h0)
//   y = tanh(h)@W_out + x@W_skip
// Outputs: next_h [T,R] fp32, y [T,D] fp32 (concat in d_out)

#define T_DIM 8192
#define D_DIM 2048
#define R_DIM 2048
#define NCH   128          // scan chunks
#define LCH   64           // T_DIM / NCH

typedef _Float16 f16;
typedef _Float16 f16x2 __attribute__((ext_vector_type(2)));
typedef _Float16 f16x4 __attribute__((ext_vector_type(4)));
typedef _Float16 f16x8 __attribute__((ext_vector_type(8)));
typedef float    f32x4 __attribute__((ext_vector_type(4)));

#define AS1 __attribute__((address_space(1)))
#define AS3 __attribute__((address_space(3)))
// async global->LDS, 16B per lane, dest = wave-uniform base + lane*16
#define GLOAD_LDS16(g, l) \
  __builtin_amdgcn_global_load_lds((const AS1 void*)(g), (AS3 void*)(l), 16, 0, 0)

// ---------------- conversion kernels ----------------

__global__ __launch_bounds__(256) void cvt_f32_f16_kernel(
    const float* __restrict__ in, f16* __restrict__ out, int n4) {
  int i = blockIdx.x * 256 + threadIdx.x;
  if (i >= n4) return;
  float4 v = ((const float4*)in)[i];
  f16x4 o; o.x = (f16)v.x; o.y = (f16)v.y; o.z = (f16)v.z; o.w = (f16)v.w;
  ((f16x4*)out)[i] = o;
}

// in: [2048][2048] fp32 -> out: [2048][2048] fp16, transposed (out = in^T)
__global__ __launch_bounds__(256) void transpose_cvt_kernel(
    const float* __restrict__ in, f16* __restrict__ out) {
  __shared__ float tile[32][33];               // +1 pad: conflict-free transpose read
  int bx = blockIdx.x * 32, by = blockIdx.y * 32;
  int tx = threadIdx.x, ty = threadIdx.y;      // block (32,8)
  #pragma unroll
  for (int i = 0; i < 32; i += 8)
    tile[ty + i][tx] = in[(size_t)(by + ty + i) * 2048 + bx + tx];
  __syncthreads();
  #pragma unroll
  for (int i = 0; i < 32; i += 8)
    out[(size_t)(bx + ty + i) * 2048 + by + tx] = (f16)tile[tx][ty + i];
}

// ---------------- GEMM (m97-style 128x128 tile, fp16 MFMA) ----------------
// C[M x 2048] = A1[M x K1] @ B1t^T (+ A2[M x K2] @ B2t^T), B stored transposed [N][K].
// MODE 0: store fp32. MODE 1: store sigmoid(v) fp16. MODE 2: store v*(1-aAux) fp16.
template <int MODE>
__global__ __launch_bounds__(256) void gemm_kernel(
    const f16* __restrict__ A1, const f16* __restrict__ B1, int K1,
    const f16* __restrict__ A2, const f16* __restrict__ B2, int K2,
    const f16* __restrict__ aAux, void* __restrict__ outp) {
  __shared__ f16 smA[128 * 32];
  __shared__ f16 smB[128 * 32];
  const int tid = threadIdx.x;
  const int m0 = blockIdx.y * 128, n0 = blockIdx.x * 128;
  const int l = tid & 63, w = tid >> 6;
  const int wr = (w >> 1) * 64, wc = (w & 1) * 64;  // wave's 64x64 quadrant
  const int lrow = l & 15, lk = (l >> 4) * 8;

  f32x4 acc[4][4];
  #pragma unroll
  for (int m = 0; m < 4; m++)
    #pragma unroll
    for (int n = 0; n < 4; n++)
      acc[m][n] = (f32x4){0.f, 0.f, 0.f, 0.f};

  // stage a 128x32 f16 tile (linear LDS [128][32]) via global_load_lds
  auto stage = [&](const f16* g0, int ld, f16* sm) {
    #pragma unroll
    for (int j = 0; j < 2; j++) {
      const int o = tid * 8 + j * 2048;            // element offset in tile
      GLOAD_LDS16(g0 + (size_t)(o >> 5) * ld + (o & 31), sm + (o & ~511));
    }
  };

  const f16* Aps[2] = {A1, A2};
  const f16* Bps[2] = {B1, B2};
  const int  Kps[2] = {K1, K2};
  for (int p = 0; p < 2; p++) {
    const f16* A = Aps[p];
    if (A == nullptr) break;
    const f16* B = Bps[p];
    const int K = Kps[p];
    const f16* Ab = A + (size_t)m0 * K;
    const f16* Bb = B + (size_t)n0 * K;
    for (int kt = 0; kt < K; kt += 32) {
      stage(Ab + kt, K, smA);
      stage(Bb + kt, K, smB);
      __syncthreads();
      f16x8 aF[4], bF[4];
      #pragma unroll
      for (int m = 0; m < 4; m++)
        aF[m] = *(const f16x8*)&smA[(wr + m * 16 + lrow) * 32 + lk];
      #pragma unroll
      for (int n = 0; n < 4; n++)
        bF[n] = *(const f16x8*)&smB[(wc + n * 16 + lrow) * 32 + lk];
      #pragma unroll
      for (int m = 0; m < 4; m++)
        #pragma unroll
        for (int n = 0; n < 4; n++)
          acc[m][n] = __builtin_amdgcn_mfma_f32_16x16x32_f16(aF[m], bF[n], acc[m][n], 0, 0, 0);
      __syncthreads();
    }
  }

  // epilogue; C/D layout: col = lane&15, row = (lane>>4)*4 + reg
  const int r0 = m0 + wr + (l >> 4) * 4;
  const int c0 = n0 + wc + lrow;
  #pragma unroll
  for (int m = 0; m < 4; m++)
    #pragma unroll
    for (int n = 0; n < 4; n++)
      #pragma unroll
      for (int j = 0; j < 4; j++) {
        size_t idx = (size_t)(r0 + m * 16 + j) * 2048 + (c0 + n * 16);
        float v = acc[m][n][j];
        if (MODE == 0) {
          ((float*)outp)[idx] = v;
        } else if (MODE == 1) {
          ((f16*)outp)[idx] = (f16)(1.0f / (1.0f + __expf(-v)));
        } else {
          ((f16*)outp)[idx] = (f16)(v * (1.0f - (float)aAux[idx]));
        }
      }
}

// ---------------- chunked scan: h_t = a_t*h_{t-1} + b_t ----------------
// Each thread owns 2 adjacent columns (4B coalesced f16x2 loads).

__global__ __launch_bounds__(256) void scan_pass_a(
    const f16* __restrict__ a, const f16* __restrict__ b,
    float* __restrict__ Ac, float* __restrict__ Bc) {
  int tid = blockIdx.x * 256 + threadIdx.x;   // NCH * R/2 threads
  int c  = tid >> 10;                          // / (R_DIM/2)
  int r2 = (tid & 1023) << 1;
  const f16* pa = a + (size_t)c * LCH * R_DIM + r2;
  const f16* pb = b + (size_t)c * LCH * R_DIM + r2;
  float A0 = 1.f, B0 = 0.f, A1 = 1.f, B1 = 0.f;
  #pragma unroll 8
  for (int i = 0; i < LCH; i++) {
    f16x2 av = *(const f16x2*)(pa + (size_t)i * R_DIM);
    f16x2 bv = *(const f16x2*)(pb + (size_t)i * R_DIM);
    float a0 = (float)av.x, a1 = (float)av.y;
    B0 = fmaf(a0, B0, (float)bv.x); A0 *= a0;
    B1 = fmaf(a1, B1, (float)bv.y); A1 *= a1;
  }
  size_t o = (size_t)c * R_DIM + r2;
  *(float2*)&Ac[o] = make_float2(A0, A1);
  *(float2*)&Bc[o] = make_float2(B0, B1);
}

__global__ __launch_bounds__(256) void scan_carry(
    const float* __restrict__ Ac, const float* __restrict__ Bc,
    const float* __restrict__ h0, float* __restrict__ carry) {
  int r = blockIdx.x * 256 + threadIdx.x;     // R threads
  float h = h0[r];
  for (int c = 0; c < NCH; c++) {
    size_t o = (size_t)c * R_DIM + r;
    carry[o] = h;                              // h at chunk start
    h = fmaf(Ac[o], h, Bc[o]);
  }
}

__global__ __launch_bounds__(256) void scan_pass_c(
    const f16* __restrict__ a, const f16* __restrict__ b,
    const float* __restrict__ carry,
    float* __restrict__ hout, f16* __restrict__ th) {
  int tid = blockIdx.x * 256 + threadIdx.x;
  int c  = tid >> 10;
  int r2 = (tid & 1023) << 1;
  size_t base = (size_t)c * LCH * R_DIM + r2;
  const f16* pa = a + base;
  const f16* pb = b + base;
  float2 hv = *(const float2*)&carry[(size_t)c * R_DIM + r2];
  float hA = hv.x, hB = hv.y;
  #pragma unroll 4
  for (int i = 0; i < LCH; i++) {
    f16x2 av = *(const f16x2*)(pa + (size_t)i * R_DIM);
    f16x2 bv = *(const f16x2*)(pb + (size_t)i * R_DIM);
    hA = fmaf((float)av.x, hA, (float)bv.x);
    hB = fmaf((float)av.y, hB, (float)bv.y);
    size_t o = base + (size_t)i * R_DIM;
    *(float2*)&hout[o] = make_float2(hA, hB);
    f16x2 tv; tv.x = (f16)tanhf(hA); tv.y = (f16)tanhf(hB);
    *(f16x2*)(th + o) = tv;
  }
}

// ---------------- launch ----------------

extern "C" void kernel_launch(void* const* d_in, const int* in_sizes, int n_in,
                              void* d_out, int out_size, void* d_ws, size_t ws_size,
                              hipStream_t stream) {
  const float* x      = (const float*)d_in[0];
  const float* h0     = (const float*)d_in[1];
  const float* W_a    = (const float*)d_in[2];
  const float* W_b    = (const float*)d_in[3];
  const float* W_out  = (const float*)d_in[4];
  const float* W_skip = (const float*)d_in[5];
  float* out_h = (float*)d_out;                       // [T,R]
  float* out_y = out_h + (size_t)T_DIM * R_DIM;       // [T,D]

  char* ws = (char*)d_ws;
  size_t off = 0;
  auto alloc = [&](size_t bytes) -> void* {
    void* p = ws + off;
    off += (bytes + 255) & ~(size_t)255;
    return p;
  };
  f16*  x16   = (f16*)alloc((size_t)T_DIM * D_DIM * 2);   // 33.6 MB
  f16*  WaT   = (f16*)alloc((size_t)D_DIM * R_DIM * 2);   // 8.4 MB (W_a^T [R][D])
  f16*  WbT   = (f16*)alloc((size_t)D_DIM * R_DIM * 2);
  f16*  WoutT = (f16*)alloc((size_t)R_DIM * D_DIM * 2);   // W_out^T [D][R]
  f16*  WskT  = (f16*)alloc((size_t)D_DIM * D_DIM * 2);
  f16*  a16   = (f16*)alloc((size_t)T_DIM * R_DIM * 2);   // 33.6 MB
  f16*  b16   = (f16*)alloc((size_t)T_DIM * R_DIM * 2);
  f16*  th16  = (f16*)alloc((size_t)T_DIM * R_DIM * 2);   // tanh(h) fp16
  float* Ac   = (float*)alloc((size_t)NCH * R_DIM * 4);
  float* Bc   = (float*)alloc((size_t)NCH * R_DIM * 4);
  float* carry= (float*)alloc((size_t)NCH * R_DIM * 4);
  // total ~172 MB

  // 1) fp32 -> fp16 conversions (x) and transposed weights (B^T layout for GEMM)
  {
    int n4 = T_DIM * D_DIM / 4;
    cvt_f32_f16_kernel<<<(n4 + 255) / 256, 256, 0, stream>>>(x, x16, n4);
  }
  dim3 tg(64, 64), tb(32, 8);
  transpose_cvt_kernel<<<tg, tb, 0, stream>>>(W_a,    WaT);
  transpose_cvt_kernel<<<tg, tb, 0, stream>>>(W_b,    WbT);
  transpose_cvt_kernel<<<tg, tb, 0, stream>>>(W_out,  WoutT);
  transpose_cvt_kernel<<<tg, tb, 0, stream>>>(W_skip, WskT);

  // 2) a = sigmoid(x@W_a); b = (x@W_b)*(1-a)   (epilogue-fused)
  dim3 gg(R_DIM / 128, T_DIM / 128);  // (16, 64)
  gemm_kernel<1><<<gg, 256, 0, stream>>>(x16, WaT, D_DIM, nullptr, nullptr, 0, nullptr, a16);
  gemm_kernel<2><<<gg, 256, 0, stream>>>(x16, WbT, D_DIM, nullptr, nullptr, 0, a16,    b16);

  // 3) chunked scan -> next_h (fp32, d_out) and tanh(h) (fp16)
  scan_pass_a<<<NCH * (R_DIM / 2) / 256, 256, 0, stream>>>(a16, b16, Ac, Bc);
  scan_carry <<<R_DIM / 256, 256, 0, stream>>>(Ac, Bc, h0, carry);
  scan_pass_c<<<NCH * (R_DIM / 2) / 256, 256, 0, stream>>>(a16, b16, carry, out_h, th16);

  // 4) y = tanh(h)@W_out + x@W_skip  (K-concatenated dual-pair GEMM)
  gemm_kernel<0><<<gg, 256, 0, stream>>>(th16, WoutT, R_DIM, x16, WskT, D_DIM, nullptr, out_y);
}

// Round 2
// 563.097 us; speedup vs baseline: 1.3232x; 1.3232x over previous
//
#include <hip/hip_runtime.h>
#include <hip/hip_fp16.h>

// Problem: T=8192, D=2048, R=2048
//   a = sigmoid(x@W_a); b = (x@W_b)*(1-a)
//   h_t = a_t*h_{t-1} + b_t  (h_{-1} = h0)
//   y = tanh(h)@W_out + x@W_skip
// Outputs: next_h [T,R] fp32, y [T,D] fp32 (concat in d_out)

#define T_DIM 8192
#define D_DIM 2048
#define R_DIM 2048
#define NCH   128          // scan chunks
#define LCH   64           // T_DIM / NCH

typedef _Float16 f16;
typedef _Float16 f16x2 __attribute__((ext_vector_type(2)));
typedef _Float16 f16x4 __attribute__((ext_vector_type(4)));
typedef _Float16 f16x8 __attribute__((ext_vector_type(8)));
typedef float    f32x4 __attribute__((ext_vector_type(4)));

#define AS1 __attribute__((address_space(1)))
#define AS3 __attribute__((address_space(3)))
// async global->LDS, 16B per lane, dest = wave-uniform base + lane*16
#define GLOAD_LDS16(g, l) \
  __builtin_amdgcn_global_load_lds((const AS1 void*)(g), (AS3 void*)(l), 16, 0, 0)

// LDS XOR swizzle: involution (modifies bits 4-6 from untouched bits 7-9).
// [256][32]f16 tile: 16 consecutive rows -> all 8 16B slots 2-way (free).
__device__ __forceinline__ int swz(int p) { return p ^ (((p >> 7) & 7) << 4); }

// ---------------- conversion kernels ----------------

__global__ __launch_bounds__(256) void cvt_f32_f16_kernel(
    const float* __restrict__ in, f16* __restrict__ out, int n4) {
  int i = blockIdx.x * 256 + threadIdx.x;
  if (i >= n4) return;
  float4 v = ((const float4*)in)[i];
  f16x4 o; o.x = (f16)v.x; o.y = (f16)v.y; o.z = (f16)v.z; o.w = (f16)v.w;
  ((f16x4*)out)[i] = o;
}

// in: [2048][2048] fp32 -> out: [2048][2048] fp16, transposed (out = in^T)
__global__ __launch_bounds__(256) void transpose_cvt_kernel(
    const float* __restrict__ in, f16* __restrict__ out) {
  __shared__ float tile[32][33];
  int bx = blockIdx.x * 32, by = blockIdx.y * 32;
  int tx = threadIdx.x, ty = threadIdx.y;      // block (32,8)
  #pragma unroll
  for (int i = 0; i < 32; i += 8)
    tile[ty + i][tx] = in[(size_t)(by + ty + i) * 2048 + bx + tx];
  __syncthreads();
  #pragma unroll
  for (int i = 0; i < 32; i += 8)
    out[(size_t)(bx + ty + i) * 2048 + by + tx] = (f16)tile[tx][ty + i];
}

// ---------------- GEMM: 256x256 tile, BK=32, 8 waves, 4-buffer pipeline --------
// C[8192 x 2048] = A1 @ B1^T (+ A2 @ B2^T); A [M][2048] f16, B stored [N][2048] f16.
// Pipeline: prefetch distance 3 K-tiles, 4 LDS buffers, ONE barrier + ONE counted
// vmcnt per tile (no drain-0 in steady state). LDS reads XOR-swizzled (T2),
// staged via pre-swizzled per-lane global source (linear global_load_lds dest).
// MODE 0: store fp32. MODE 1: store sigmoid(v) f16. MODE 2: store v*(1-aAux) f16.
template <int MODE>
__global__ __launch_bounds__(512, 2) void gemm_kernel(
    const f16* __restrict__ A1, const f16* __restrict__ B1, int NT1,
    const f16* __restrict__ A2, const f16* __restrict__ B2, int NT2,
    const f16* __restrict__ aAux, void* __restrict__ outp) {
  __shared__ __align__(16) char lds[4 * 32768];   // 4 bufs x (A 16KB + B 16KB)
  const int tid = threadIdx.x;
  const int l = tid & 63, w = tid >> 6;           // 8 waves
  const int wrow = w >> 2, wcol = w & 3;          // 2 x 4 wave grid
  const int l15 = l & 15, kq = (l >> 4) * 16;     // frag row / k-byte within tile

  // chunked XCD swizzle: grid 256 = 8 (N) x 32 (M); XCD k -> 4 contiguous row-panels
  const int id = blockIdx.x;
  const int sw = (id & 7) * 32 + (id >> 3);
  const int m0 = (sw >> 3) * 256, n0 = (sw & 7) * 256;
  const int NTtot = NT1 + NT2;

  // per-lane staging source offsets (bytes): chunk c=q*512+tid, phys p=c*16 (local
  // to 16KB buf), logical = swz(p) -> (row, kbyte); row stride = 2048*2 = 4096 B.
  int gOff[2];
  #pragma unroll
  for (int q = 0; q < 2; q++) {
    int p = (q * 512 + tid) * 16 & 16383;
    int lg = swz(p);
    gOff[q] = (lg >> 6) * 4096 + (lg & 63);
  }
  // per-lane swizzled LDS read offsets (constant per buffer)
  int oA[8], oB[4];
  #pragma unroll
  for (int m = 0; m < 8; m++)
    oA[m] = swz((wrow * 128 + m * 16 + l15) * 64 + kq);
  #pragma unroll
  for (int n = 0; n < 4; n++)
    oB[n] = swz((wcol * 64 + n * 16 + l15) * 64 + kq);

  f32x4 acc[8][4];
  #pragma unroll
  for (int m = 0; m < 8; m++)
    #pragma unroll
    for (int n = 0; n < 4; n++)
      acc[m][n] = (f32x4){0.f, 0.f, 0.f, 0.f};

  auto stage = [&](int tf) {
    const f16* At; const f16* Bt; int kt;
    if (tf < NT1) { At = A1; Bt = B1; kt = tf; }
    else          { At = A2; Bt = B2; kt = tf - NT1; }
    const char* gA = (const char*)(At + (size_t)m0 * 2048 + kt * 32);
    const char* gB = (const char*)(Bt + (size_t)n0 * 2048 + kt * 32);
    char* ldsA = lds + (tf & 3) * 32768;
    char* ldsB = ldsA + 16384;
    #pragma unroll
    for (int q = 0; q < 2; q++) {
      GLOAD_LDS16(gA + gOff[q], ldsA + (q * 512 + w * 64) * 16);
      GLOAD_LDS16(gB + gOff[q], ldsB + (q * 512 + w * 64) * 16);
    }
  };

  // prologue: 3 tiles in flight (12 gloads/wave)
  stage(0); stage(1); stage(2);

  for (int t = 0; t < NTtot; ++t) {
    // wait for tile t (own 4 loads), leave tiles t+1,t+2 in flight
    const int rem = NTtot - 1 - t;
    if (rem >= 2)      asm volatile("s_waitcnt vmcnt(8)" ::: "memory");
    else if (rem == 1) asm volatile("s_waitcnt vmcnt(4)" ::: "memory");
    else               asm volatile("s_waitcnt vmcnt(0)" ::: "memory");
    asm volatile("s_barrier" ::: "memory");   // all waves' tile-t stores visible
    if (t + 3 < NTtot) stage(t + 3);          // into buf[(t-1)&3], readers done

    const char* bA = lds + (t & 3) * 32768;
    const char* bB = bA + 16384;
    f16x8 af[8], bf[4];
    #pragma unroll
    for (int m = 0; m < 8; m++) af[m] = *(const f16x8*)(bA + oA[m]);
    #pragma unroll
    for (int n = 0; n < 4; n++) bf[n] = *(const f16x8*)(bB + oB[n]);
    __builtin_amdgcn_s_setprio(1);
    #pragma unroll
    for (int m = 0; m < 8; m++)
      #pragma unroll
      for (int n = 0; n < 4; n++)
        acc[m][n] = __builtin_amdgcn_mfma_f32_16x16x32_f16(af[m], bf[n], acc[m][n], 0, 0, 0);
    __builtin_amdgcn_s_setprio(0);
  }

  // epilogue; C/D layout: col = lane&15, row = (lane>>4)*4 + reg
  const int r0 = m0 + wrow * 128 + (l >> 4) * 4;
  const int c0 = n0 + wcol * 64 + l15;
  #pragma unroll
  for (int m = 0; m < 8; m++)
    #pragma unroll
    for (int n = 0; n < 4; n++)
      #pragma unroll
      for (int j = 0; j < 4; j++) {
        size_t idx = (size_t)(r0 + m * 16 + j) * 2048 + (c0 + n * 16);
        float v = acc[m][n][j];
        if (MODE == 0) {
          ((float*)outp)[idx] = v;
        } else if (MODE == 1) {
          ((f16*)outp)[idx] = (f16)(1.0f / (1.0f + __expf(-v)));
        } else {
          ((f16*)outp)[idx] = (f16)(v * (1.0f - (float)aAux[idx]));
        }
      }
}

// ---------------- chunked scan: h_t = a_t*h_{t-1} + b_t ----------------

__global__ __launch_bounds__(256) void scan_pass_a(
    const f16* __restrict__ a, const f16* __restrict__ b,
    float* __restrict__ Ac, float* __restrict__ Bc) {
  int tid = blockIdx.x * 256 + threadIdx.x;   // NCH * R/2 threads
  int c  = tid >> 10;
  int r2 = (tid & 1023) << 1;
  const f16* pa = a + (size_t)c * LCH * R_DIM + r2;
  const f16* pb = b + (size_t)c * LCH * R_DIM + r2;
  float A0 = 1.f, B0 = 0.f, A1 = 1.f, B1 = 0.f;
  #pragma unroll 8
  for (int i = 0; i < LCH; i++) {
    f16x2 av = *(const f16x2*)(pa + (size_t)i * R_DIM);
    f16x2 bv = *(const f16x2*)(pb + (size_t)i * R_DIM);
    float a0 = (float)av.x, a1 = (float)av.y;
    B0 = fmaf(a0, B0, (float)bv.x); A0 *= a0;
    B1 = fmaf(a1, B1, (float)bv.y); A1 *= a1;
  }
  size_t o = (size_t)c * R_DIM + r2;
  *(float2*)&Ac[o] = make_float2(A0, A1);
  *(float2*)&Bc[o] = make_float2(B0, B1);
}

__global__ __launch_bounds__(256) void scan_carry(
    const float* __restrict__ Ac, const float* __restrict__ Bc,
    const float* __restrict__ h0, float* __restrict__ carry) {
  int r = blockIdx.x * 256 + threadIdx.x;     // R threads
  float h = h0[r];
  #pragma unroll 8
  for (int c = 0; c < NCH; c++) {
    size_t o = (size_t)c * R_DIM + r;
    carry[o] = h;
    h = fmaf(Ac[o], h, Bc[o]);
  }
}

__global__ __launch_bounds__(256) void scan_pass_c(
    const f16* __restrict__ a, const f16* __restrict__ b,
    const float* __restrict__ carry,
    float* __restrict__ hout, f16* __restrict__ th) {
  int tid = blockIdx.x * 256 + threadIdx.x;
  int c  = tid >> 10;
  int r2 = (tid & 1023) << 1;
  size_t base = (size_t)c * LCH * R_DIM + r2;
  const f16* pa = a + base;
  const f16* pb = b + base;
  float2 hv = *(const float2*)&carry[(size_t)c * R_DIM + r2];
  float hA = hv.x, hB = hv.y;
  #pragma unroll 4
  for (int i = 0; i < LCH; i++) {
    f16x2 av = *(const f16x2*)(pa + (size_t)i * R_DIM);
    f16x2 bv = *(const f16x2*)(pb + (size_t)i * R_DIM);
    hA = fmaf((float)av.x, hA, (float)bv.x);
    hB = fmaf((float)av.y, hB, (float)bv.y);
    size_t o = base + (size_t)i * R_DIM;
    *(float2*)&hout[o] = make_float2(hA, hB);
    f16x2 tv; tv.x = (f16)tanhf(hA); tv.y = (f16)tanhf(hB);
    *(f16x2*)(th + o) = tv;
  }
}

// ---------------- launch ----------------

extern "C" void kernel_launch(void* const* d_in, const int* in_sizes, int n_in,
                              void* d_out, int out_size, void* d_ws, size_t ws_size,
                              hipStream_t stream) {
  const float* x      = (const float*)d_in[0];
  const float* h0     = (const float*)d_in[1];
  const float* W_a    = (const float*)d_in[2];
  const float* W_b    = (const float*)d_in[3];
  const float* W_out  = (const float*)d_in[4];
  const float* W_skip = (const float*)d_in[5];
  float* out_h = (float*)d_out;                       // [T,R]
  float* out_y = out_h + (size_t)T_DIM * R_DIM;       // [T,D]

  char* ws = (char*)d_ws;
  size_t off = 0;
  auto alloc = [&](size_t bytes) -> void* {
    void* p = ws + off;
    off += (bytes + 255) & ~(size_t)255;
    return p;
  };
  f16*  x16   = (f16*)alloc((size_t)T_DIM * D_DIM * 2);
  f16*  WaT   = (f16*)alloc((size_t)D_DIM * R_DIM * 2);
  f16*  WbT   = (f16*)alloc((size_t)D_DIM * R_DIM * 2);
  f16*  WoutT = (f16*)alloc((size_t)R_DIM * D_DIM * 2);
  f16*  WskT  = (f16*)alloc((size_t)D_DIM * D_DIM * 2);
  f16*  a16   = (f16*)alloc((size_t)T_DIM * R_DIM * 2);
  f16*  b16   = (f16*)alloc((size_t)T_DIM * R_DIM * 2);
  f16*  th16  = (f16*)alloc((size_t)T_DIM * R_DIM * 2);
  float* Ac   = (float*)alloc((size_t)NCH * R_DIM * 4);
  float* Bc   = (float*)alloc((size_t)NCH * R_DIM * 4);
  float* carry= (float*)alloc((size_t)NCH * R_DIM * 4);

  // 1) fp32 -> fp16 conversions and transposed weights
  {
    int n4 = T_DIM * D_DIM / 4;
    cvt_f32_f16_kernel<<<(n4 + 255) / 256, 256, 0, stream>>>(x, x16, n4);
  }
  dim3 tg(64, 64), tb(32, 8);
  transpose_cvt_kernel<<<tg, tb, 0, stream>>>(W_a,    WaT);
  transpose_cvt_kernel<<<tg, tb, 0, stream>>>(W_b,    WbT);
  transpose_cvt_kernel<<<tg, tb, 0, stream>>>(W_out,  WoutT);
  transpose_cvt_kernel<<<tg, tb, 0, stream>>>(W_skip, WskT);

  // 2) a = sigmoid(x@W_a); b = (x@W_b)*(1-a)   (epilogue-fused)
  const int NT = D_DIM / 32;  // 64 K-tiles per 2048-deep panel
  gemm_kernel<1><<<256, 512, 0, stream>>>(x16, WaT, NT, nullptr, nullptr, 0, nullptr, a16);
  gemm_kernel<2><<<256, 512, 0, stream>>>(x16, WbT, NT, nullptr, nullptr, 0, a16,    b16);

  // 3) chunked scan -> next_h (fp32, d_out) and tanh(h) (fp16)
  scan_pass_a<<<NCH * (R_DIM / 2) / 256, 256, 0, stream>>>(a16, b16, Ac, Bc);
  scan_carry <<<R_DIM / 256, 256, 0, stream>>>(Ac, Bc, h0, carry);
  scan_pass_c<<<NCH * (R_DIM / 2) / 256, 256, 0, stream>>>(a16, b16, carry, out_h, th16);

  // 4) y = tanh(h)@W_out + x@W_skip  (K-concatenated dual-panel GEMM)
  gemm_kernel<0><<<256, 512, 0, stream>>>(th16, WoutT, NT, x16, WskT, NT, nullptr, out_y);
}